// Round 7
// baseline (120.691 us; speedup 1.0000x reference)
//
#include <hip/hip_runtime.h>
#include <hip/hip_bf16.h>
#include <math.h>

// Problem constants (from the reference)
#define NALT      8
#define BDIM      8
#define CDIM      4
#define RDIM      512
#define OUT_HALF  (BDIM * CDIM * RDIM * NALT)   // 131072 floats
#define OUT_TOTAL (2 * OUT_HALF)                // 262144 floats [MC | SC]

// Deterministic 3-step binning, half-atom granularity (no global atomics):
//  bucket = b*4+c (32); half-record = { u16 lidx, uint2 = 4 x bf16 }
//  lidx = bb*4096 + r*8 + half*4
#define NBUCKET 32
#define CAP     131072        // half-records per bucket (4M/32 = 125K avg + 12 sigma)
#define LSLOTS  8192          // pass-B LDS tile: bb(2)*r(512)*alt(8) f32 = 32 KiB
#define AITER   4             // atoms/thread in count  (1024 atoms/block)
#define HITER   8             // half-atoms/thread in place (2048 halves = 1024 atoms/block)
#define MAXBLK  2048

// ws layout:
//   [0,    256K) : cntArr  u32 [MAXBLK][NBUCKET]   (half-record counts)
//   [256K, 512K) : baseArr u32 [MAXBLK][NBUCKET]
//   [512K, +4K ) : totals  u32 [NBUCKET]
//   [+,    +8M ) : slotArr u16 [NBUCKET][CAP]
//   [+,    +32M) : valArr  uint2[NBUCKET][CAP]
//   [+, +nsplit*1M) : partial f32 [NBUCKET*nsplit][LSLOTS]
#define WS_CNT_OFF   0
#define WS_BASE_OFF  (256 * 1024)
#define WS_TOT_OFF   (512 * 1024)
#define WS_SLOT_OFF  (512 * 1024 + 4096)
#define WS_VAL_OFF   (WS_SLOT_OFF + (size_t)NBUCKET * CAP * 2)
#define WS_PART_OFF  (WS_VAL_OFF + (size_t)NBUCKET * CAP * 8)

__device__ __forceinline__ unsigned int pack_bf16_2(float a, float b) {
    unsigned int ua = __float_as_uint(a);
    unsigned int ub = __float_as_uint(b);
    ua = (ua + 0x7fffu + ((ua >> 16) & 1u)) >> 16;   // round-to-nearest-even
    ub = (ub + 0x7fffu + ((ub >> 16) & 1u)) >> 16;
    return ua | (ub << 16);
}

// K1: per-(block,bucket) histogram over atoms; stores 2x (half-record counts).
__global__ void __launch_bounds__(256) vdw_count_kernel(
    const int4* __restrict__ desc,
    unsigned int* __restrict__ cntArr,
    int n)
{
    __shared__ int cnt[NBUCKET];
    const int tid = threadIdx.x;
    if (tid < NBUCKET) cnt[tid] = 0;
    __syncthreads();

    const int a_begin = blockIdx.x * (256 * AITER);
    #pragma unroll
    for (int it = 0; it < AITER; ++it) {
        const int a = a_begin + it * 256 + tid;
        if (a < n) {
            const int4 d = desc[a];
            if (d.w != -1) atomicAdd(&cnt[d.y * CDIM + d.z], 1);
        }
    }
    __syncthreads();
    if (tid < NBUCKET)
        cntArr[blockIdx.x * NBUCKET + tid] = 2u * (unsigned int)cnt[tid];
}

// K2: per-bucket exclusive scan over blocks -> baseArr, totals.
__global__ void __launch_bounds__(256) vdw_prefix_kernel(
    const unsigned int* __restrict__ cntArr,
    unsigned int* __restrict__ baseArr,
    unsigned int* __restrict__ totals,
    int nblocks)
{
    __shared__ unsigned int s[256];
    __shared__ unsigned int carry;
    const int j   = blockIdx.x;
    const int tid = threadIdx.x;
    if (tid == 0) carry = 0;
    __syncthreads();

    for (int i0 = 0; i0 < nblocks; i0 += 256) {
        const int i = i0 + tid;
        const unsigned int c0 = carry;
        const unsigned int v  = (i < nblocks) ? cntArr[i * NBUCKET + j] : 0u;
        s[tid] = v;
        __syncthreads();
        #pragma unroll
        for (int off = 1; off < 256; off <<= 1) {
            const unsigned int t = (tid >= off) ? s[tid - off] : 0u;
            __syncthreads();
            s[tid] += t;
            __syncthreads();
        }
        if (i < nblocks) baseArr[i * NBUCKET + j] = c0 + s[tid] - v;
        __syncthreads();
        if (tid == 0) carry = c0 + s[255];
        __syncthreads();
    }
    if (tid == 0) totals[j] = carry;
}

// K3: place, HALF-ATOM per lane. facc/mask loads are perfectly coalesced
// (16B/lane contiguous); desc is a 2-lane-shared coalesced read.
__global__ void __launch_bounds__(256) vdw_place_kernel(
    const int4*   __restrict__ desc,
    const int4*   __restrict__ mask,    // 1 int4 per half-atom
    const float4* __restrict__ facc,    // 1 float4 per half-atom
    const float*  __restrict__ props,
    const float*  __restrict__ weight,
    const unsigned int* __restrict__ baseArr,
    unsigned short* __restrict__ slotArr,
    uint2*        __restrict__ valArr,
    int n)
{
    __shared__ int cnt[NBUCKET];
    const int tid = threadIdx.x;
    if (tid < NBUCKET) cnt[tid] = 0;
    __syncthreads();

    const float scale = (1.0f - tanhf(weight[0])) * 0.3f;
    const int h_begin = blockIdx.x * (256 * HITER);
    const int h_end   = 2 * n;
    const unsigned int* myBase = baseArr + blockIdx.x * NBUCKET;

    #pragma unroll
    for (int it = 0; it < HITER; ++it) {
        const int h = h_begin + it * 256 + tid;
        if (h >= h_end) continue;
        const int a    = h >> 1;
        const int half = h & 1;
        const int4 d = desc[a];
        if (d.w == -1) continue;

        const float vs  = props[d.x * 8] * scale;
        const int bkt   = d.y * CDIM + d.z;
        const int lidx  = ((d.x < 4) ? 0 : 4096) + d.w * 8 + half * 4;

        const float4 f = facc[h];
        const int4   m = mask[h];
        const float v0 = m.x ? vs * fmaxf(f.x, 0.0f) : 0.0f;
        const float v1 = m.y ? vs * fmaxf(f.y, 0.0f) : 0.0f;
        const float v2 = m.z ? vs * fmaxf(f.z, 0.0f) : 0.0f;
        const float v3 = m.w ? vs * fmaxf(f.w, 0.0f) : 0.0f;
        const uint2 rv = make_uint2(pack_bf16_2(v0, v1), pack_bf16_2(v2, v3));

        const int loc = atomicAdd(&cnt[bkt], 1);
        const unsigned int pos = myBase[bkt] + (unsigned int)loc;
        if (pos < CAP) {
            slotArr[bkt * CAP + pos]        = (unsigned short)lidx;
            valArr[(size_t)bkt * CAP + pos] = rv;
        }
    }
}

// K4: per (bucket, split) block: accumulate half-records into 32 KiB LDS tile,
// write dense partial.
__global__ void __launch_bounds__(256) vdw_accum_kernel(
    const unsigned short* __restrict__ slotArr,
    const uint2*          __restrict__ valArr,
    const unsigned int*   __restrict__ totals,
    float*                __restrict__ partial,
    int nsplit)
{
    __shared__ float acc[LSLOTS];
    const int tid = threadIdx.x;
    for (int k = tid; k < LSLOTS; k += 256) acc[k] = 0.0f;
    __syncthreads();

    const int bucket = blockIdx.x / nsplit;
    const int split  = blockIdx.x % nsplit;
    int count = (int)totals[bucket];
    if (count > CAP) count = CAP;
    const int per = (count + nsplit - 1) / nsplit;
    const int r0  = split * per;
    int r1 = r0 + per;
    if (r1 > count) r1 = count;

    const unsigned short* sa = slotArr + bucket * CAP;
    const uint2*          va = valArr  + (size_t)bucket * CAP;

    for (int rec = r0 + tid; rec < r1; rec += 256) {
        const int   l = sa[rec];
        const uint2 v = va[rec];
        float t;
        t = __uint_as_float(v.x << 16);          if (t != 0.0f) atomicAdd(&acc[l + 0], t);
        t = __uint_as_float(v.x & 0xffff0000u);  if (t != 0.0f) atomicAdd(&acc[l + 1], t);
        t = __uint_as_float(v.y << 16);          if (t != 0.0f) atomicAdd(&acc[l + 2], t);
        t = __uint_as_float(v.y & 0xffff0000u);  if (t != 0.0f) atomicAdd(&acc[l + 3], t);
    }
    __syncthreads();

    float* dst = partial + (size_t)blockIdx.x * LSLOTS;
    for (int k = tid; k < LSLOTS; k += 256) dst[k] = acc[k];
}

// K5: out[idx] = sum over splits of matching partial. Writes every element.
__global__ void __launch_bounds__(256) vdw_merge_kernel(
    const float* __restrict__ partial,
    float*       __restrict__ out,
    int nsplit)
{
    const int idx = blockIdx.x * 256 + threadIdx.x;
    if (idx >= OUT_TOTAL) return;
    // idx = (((bb*8+b)*4+c)*512 + r)*8 + alt
    const int bb     = idx >> 17;
    const int b      = (idx >> 14) & 7;
    const int c      = (idx >> 12) & 3;
    const int lidx   = bb * 4096 + (idx & 4095);   // r*8+alt
    const int bucket = b * CDIM + c;
    const float* p = partial + ((size_t)bucket * nsplit) * LSLOTS + lidx;
    float s = 0.0f;
    for (int sp = 0; sp < nsplit; ++sp)
        s += p[(size_t)sp * LSLOTS];
    out[idx] = s;
}

// Fallback (small ws): direct global atomics into d_out.
__global__ void __launch_bounds__(256) vdw_atomic_kernel(
    const int*   __restrict__ desc,
    const int*   __restrict__ mask,
    const float* __restrict__ facc,
    const float* __restrict__ props,
    const float* __restrict__ weight,
    float*       __restrict__ out,
    int n)
{
    const int i = blockIdx.x * blockDim.x + threadIdx.x;
    if (i >= n) return;
    const float scale = (1.0f - tanhf(weight[0])) * 0.3f;
    const int4 d = reinterpret_cast<const int4*>(desc)[i];
    if (d.w == -1) return;
    const float vs = props[d.x * 8 + 0] * scale;
    const int   bb = (d.x >= 0 && d.x <= 3) ? 0 : 1;
    float* base = out + bb * OUT_HALF + (((d.y * CDIM + d.z) * RDIM + d.w) * NALT);
    const float4 f0 = reinterpret_cast<const float4*>(facc)[i * 2 + 0];
    const float4 f1 = reinterpret_cast<const float4*>(facc)[i * 2 + 1];
    const int4   m0 = reinterpret_cast<const int4*>(mask)[i * 2 + 0];
    const int4   m1 = reinterpret_cast<const int4*>(mask)[i * 2 + 1];
    if (m0.x) atomicAdd(base + 0, vs * fmaxf(f0.x, 0.0f));
    if (m0.y) atomicAdd(base + 1, vs * fmaxf(f0.y, 0.0f));
    if (m0.z) atomicAdd(base + 2, vs * fmaxf(f0.z, 0.0f));
    if (m0.w) atomicAdd(base + 3, vs * fmaxf(f0.w, 0.0f));
    if (m1.x) atomicAdd(base + 4, vs * fmaxf(f1.x, 0.0f));
    if (m1.y) atomicAdd(base + 5, vs * fmaxf(f1.y, 0.0f));
    if (m1.z) atomicAdd(base + 6, vs * fmaxf(f1.z, 0.0f));
    if (m1.w) atomicAdd(base + 7, vs * fmaxf(f1.w, 0.0f));
}

extern "C" void kernel_launch(void* const* d_in, const int* in_sizes, int n_in,
                              void* d_out, int out_size, void* d_ws, size_t ws_size,
                              hipStream_t stream)
{
    // Inputs per setup_inputs():
    // 0: coords (unused)  1: atom_description (N,4) int32
    // 2: alternativeMask (N,8) int32  3: facc (N,8) f32
    // 4: atom_Properties (500,8) f32  5: weight (1,) f32
    const int*   desc   = (const int*)d_in[1];
    const int*   mask   = (const int*)d_in[2];
    const float* facc   = (const float*)d_in[3];
    const float* props  = (const float*)d_in[4];
    const float* weight = (const float*)d_in[5];
    float*       out    = (float*)d_out;

    const int n = in_sizes[1] / 4;
    int nblocks = (n + 256 * AITER - 1) / (256 * AITER);   // 1024 atoms/block
    if (nblocks > MAXBLK) nblocks = MAXBLK;

    // pick the largest nsplit whose partial buffer fits
    int nsplit = 0;
    for (int cand = 16; cand >= 1; cand >>= 1) {
        const size_t need = WS_PART_OFF +
            (size_t)NBUCKET * cand * LSLOTS * sizeof(float);
        if (need <= ws_size) { nsplit = cand; break; }
    }

    if (nsplit >= 1) {
        char* ws = (char*)d_ws;
        unsigned int*   cntArr  = (unsigned int*)(ws + WS_CNT_OFF);
        unsigned int*   baseArr = (unsigned int*)(ws + WS_BASE_OFF);
        unsigned int*   totals  = (unsigned int*)(ws + WS_TOT_OFF);
        unsigned short* slotArr = (unsigned short*)(ws + WS_SLOT_OFF);
        uint2*          valArr  = (uint2*)(ws + WS_VAL_OFF);
        float*          part    = (float*)(ws + WS_PART_OFF);

        vdw_count_kernel<<<nblocks, 256, 0, stream>>>(
            (const int4*)desc, cntArr, n);

        vdw_prefix_kernel<<<NBUCKET, 256, 0, stream>>>(
            cntArr, baseArr, totals, nblocks);

        vdw_place_kernel<<<nblocks, 256, 0, stream>>>(
            (const int4*)desc, (const int4*)mask, (const float4*)facc,
            props, weight, baseArr, slotArr, valArr, n);

        vdw_accum_kernel<<<NBUCKET * nsplit, 256, 0, stream>>>(
            slotArr, valArr, totals, part, nsplit);

        vdw_merge_kernel<<<(OUT_TOTAL + 255) / 256, 256, 0, stream>>>(
            part, out, nsplit);
    } else {
        hipMemsetAsync(d_out, 0, (size_t)out_size * sizeof(float), stream);
        vdw_atomic_kernel<<<(n + 255) / 256, 256, 0, stream>>>(
            desc, mask, facc, props, weight, out, n);
    }
}

// Round 8
// 88.987 us; speedup vs baseline: 1.3563x; 1.3563x over previous
//
#include <hip/hip_runtime.h>
#include <hip/hip_bf16.h>
#include <math.h>

// Problem constants (from the reference)
#define NALT      8
#define BDIM      8
#define CDIM      4
#define RDIM      512
#define OUT_HALF  (BDIM * CDIM * RDIM * NALT)   // 131072 floats
#define OUT_TOTAL (2 * OUT_HALF)                // 262144 floats [MC | SC]

#define NBUCKET   32          // bucket = b*4+c
#define BLK_ATOMS 1024        // atoms per compact block (256 thr x AITER)
#define AITER     4
#define LSLOTS    8192        // accum LDS tile: bb(2)*r(512)*alt(8) f32 = 32 KiB

// ws layout (runtime offsets, 256B-aligned):
//   hdr  u16 [nblocks][64]    (entries 0..32 = exclusive bucket offsets, [32]=total)
//   lidx u16 [nblocks][1024]
//   vals uint4[nblocks][1024]
//   partial f32 [NBUCKET*nsplit][LSLOTS]

__device__ __forceinline__ unsigned int pack_bf16_2(float a, float b) {
    unsigned int ua = __float_as_uint(a);
    unsigned int ub = __float_as_uint(b);
    ua = (ua + 0x7fffu + ((ua >> 16) & 1u)) >> 16;   // round-to-nearest-even
    ub = (ub + 0x7fffu + ((ub >> 16) & 1u)) >> 16;
    return ua | (ub << 16);
}

// K1: compact. Per block: histogram -> in-block scan -> LDS-staged records
// (scatter absorbed in LDS) -> fully coalesced block-major copy-out.
__global__ void __launch_bounds__(256) vdw_compact_kernel(
    const int4*   __restrict__ desc,
    const int4*   __restrict__ mask,
    const float4* __restrict__ facc,
    const float*  __restrict__ props,
    const float*  __restrict__ weight,
    unsigned short* __restrict__ hdrArr,   // [nblocks][64]
    unsigned short* __restrict__ lidxArr,  // [nblocks][1024]
    uint4*        __restrict__ valArr,     // [nblocks][1024]
    int n)
{
    __shared__ int            cnt[NBUCKET];
    __shared__ int            base[NBUCKET + 1];
    __shared__ unsigned short s_lidx[BLK_ATOMS];
    __shared__ uint4          s_val[BLK_ATOMS];

    const int tid = threadIdx.x;
    if (tid < NBUCKET) cnt[tid] = 0;
    __syncthreads();

    const int a0 = blockIdx.x * BLK_ATOMS;

    // pass 1: histogram (desc kept in registers)
    int4 d_[AITER];
    int  bkt[AITER];
    #pragma unroll
    for (int it = 0; it < AITER; ++it) {
        const int a = a0 + it * 256 + tid;
        bkt[it] = -1;
        if (a < n) {
            d_[it] = desc[a];
            if (d_[it].w != -1) {
                bkt[it] = d_[it].y * CDIM + d_[it].z;
                atomicAdd(&cnt[bkt[it]], 1);
            }
        }
    }
    __syncthreads();

    // exclusive scan of 32 counters (serial on thread 0 -- trivial cost)
    if (tid == 0) {
        int run = 0;
        #pragma unroll
        for (int j = 0; j < NBUCKET; ++j) { base[j] = run; run += cnt[j]; }
        base[NBUCKET] = run;
    }
    __syncthreads();
    if (tid < NBUCKET) cnt[tid] = 0;   // reuse as running slot counter
    __syncthreads();

    // pass 2: compute + stage records into LDS at bucket-grouped positions
    const float scale = (1.0f - tanhf(weight[0])) * 0.3f;
    #pragma unroll
    for (int it = 0; it < AITER; ++it) {
        if (bkt[it] < 0) continue;
        const int a  = a0 + it * 256 + tid;
        const int4 d = d_[it];
        const float vs = props[d.x * 8] * scale;
        const int lidx = ((d.x < 4) ? 0 : 4096) + d.w * 8;

        const float4 f0 = facc[a * 2 + 0];
        const float4 f1 = facc[a * 2 + 1];
        const int4   m0 = mask[a * 2 + 0];
        const int4   m1 = mask[a * 2 + 1];
        const float v0 = m0.x ? vs * fmaxf(f0.x, 0.0f) : 0.0f;
        const float v1 = m0.y ? vs * fmaxf(f0.y, 0.0f) : 0.0f;
        const float v2 = m0.z ? vs * fmaxf(f0.z, 0.0f) : 0.0f;
        const float v3 = m0.w ? vs * fmaxf(f0.w, 0.0f) : 0.0f;
        const float v4 = m1.x ? vs * fmaxf(f1.x, 0.0f) : 0.0f;
        const float v5 = m1.y ? vs * fmaxf(f1.y, 0.0f) : 0.0f;
        const float v6 = m1.z ? vs * fmaxf(f1.z, 0.0f) : 0.0f;
        const float v7 = m1.w ? vs * fmaxf(f1.w, 0.0f) : 0.0f;

        const int loc = atomicAdd(&cnt[bkt[it]], 1);
        const int pos = base[bkt[it]] + loc;
        s_lidx[pos] = (unsigned short)lidx;
        s_val[pos]  = make_uint4(pack_bf16_2(v0, v1), pack_bf16_2(v2, v3),
                                 pack_bf16_2(v4, v5), pack_bf16_2(v6, v7));
    }
    __syncthreads();

    // copy-out: fully coalesced block-major stores
    if (tid <= NBUCKET)
        hdrArr[blockIdx.x * 64 + tid] = (unsigned short)base[tid];

    unsigned int* ldst = (unsigned int*)(lidxArr + (size_t)blockIdx.x * BLK_ATOMS);
    const unsigned int* lsrc = (const unsigned int*)s_lidx;
    #pragma unroll
    for (int k = 0; k < BLK_ATOMS / 2 / 256; ++k)       // 2 iters
        ldst[k * 256 + tid] = lsrc[k * 256 + tid];

    uint4* vdst = valArr + (size_t)blockIdx.x * BLK_ATOMS;
    #pragma unroll
    for (int k = 0; k < BLK_ATOMS / 256; ++k)           // 4 iters
        vdst[k * 256 + tid] = s_val[k * 256 + tid];
}

// K2: accum. Block (bucket, split) walks its source-block range's bucket runs
// (contiguous ~512B bursts) into a 32 KiB LDS tile; writes dense partial.
__global__ void __launch_bounds__(256) vdw_accum_kernel(
    const unsigned short* __restrict__ hdrArr,
    const unsigned short* __restrict__ lidxArr,
    const uint4*          __restrict__ valArr,
    float*                __restrict__ partial,
    int nblocks, int nsplit)
{
    __shared__ float acc[LSLOTS];
    const int tid = threadIdx.x;
    for (int k = tid; k < LSLOTS; k += 256) acc[k] = 0.0f;
    __syncthreads();

    const int bucket = blockIdx.x / nsplit;
    const int split  = blockIdx.x % nsplit;
    const int per = (nblocks + nsplit - 1) / nsplit;
    const int b0  = split * per;
    const int b1  = (b0 + per < nblocks) ? (b0 + per) : nblocks;

    const int g    = tid >> 5;    // 8 groups of 32 lanes: 8 src blocks in flight
    const int lane = tid & 31;

    for (int blk = b0 + g; blk < b1; blk += 8) {
        const int start = hdrArr[blk * 64 + bucket];
        const int end   = hdrArr[blk * 64 + bucket + 1];
        const unsigned short* la = lidxArr + (size_t)blk * BLK_ATOMS;
        const uint4*          va = valArr  + (size_t)blk * BLK_ATOMS;
        for (int rec = start + lane; rec < end; rec += 32) {
            const int   l = la[rec];
            const uint4 v = va[rec];
            float t;
            t = __uint_as_float(v.x << 16);          if (t != 0.0f) atomicAdd(&acc[l + 0], t);
            t = __uint_as_float(v.x & 0xffff0000u);  if (t != 0.0f) atomicAdd(&acc[l + 1], t);
            t = __uint_as_float(v.y << 16);          if (t != 0.0f) atomicAdd(&acc[l + 2], t);
            t = __uint_as_float(v.y & 0xffff0000u);  if (t != 0.0f) atomicAdd(&acc[l + 3], t);
            t = __uint_as_float(v.z << 16);          if (t != 0.0f) atomicAdd(&acc[l + 4], t);
            t = __uint_as_float(v.z & 0xffff0000u);  if (t != 0.0f) atomicAdd(&acc[l + 5], t);
            t = __uint_as_float(v.w << 16);          if (t != 0.0f) atomicAdd(&acc[l + 6], t);
            t = __uint_as_float(v.w & 0xffff0000u);  if (t != 0.0f) atomicAdd(&acc[l + 7], t);
        }
    }
    __syncthreads();

    float* dst = partial + (size_t)blockIdx.x * LSLOTS;
    for (int k = tid; k < LSLOTS; k += 256) dst[k] = acc[k];
}

// K3: out[idx] = sum over splits of matching partial. Writes every element.
__global__ void __launch_bounds__(256) vdw_merge_kernel(
    const float* __restrict__ partial,
    float*       __restrict__ out,
    int nsplit)
{
    const int idx = blockIdx.x * 256 + threadIdx.x;
    if (idx >= OUT_TOTAL) return;
    // idx = (((bb*8+b)*4+c)*512 + r)*8 + alt
    const int bb     = idx >> 17;
    const int b      = (idx >> 14) & 7;
    const int c      = (idx >> 12) & 3;
    const int lidx   = bb * 4096 + (idx & 4095);   // r*8+alt
    const int bucket = b * CDIM + c;
    const float* p = partial + ((size_t)bucket * nsplit) * LSLOTS + lidx;
    float s = 0.0f;
    for (int sp = 0; sp < nsplit; ++sp)
        s += p[(size_t)sp * LSLOTS];
    out[idx] = s;
}

// Fallback (small ws): direct global atomics into d_out.
__global__ void __launch_bounds__(256) vdw_atomic_kernel(
    const int*   __restrict__ desc,
    const int*   __restrict__ mask,
    const float* __restrict__ facc,
    const float* __restrict__ props,
    const float* __restrict__ weight,
    float*       __restrict__ out,
    int n)
{
    const int i = blockIdx.x * blockDim.x + threadIdx.x;
    if (i >= n) return;
    const float scale = (1.0f - tanhf(weight[0])) * 0.3f;
    const int4 d = reinterpret_cast<const int4*>(desc)[i];
    if (d.w == -1) return;
    const float vs = props[d.x * 8 + 0] * scale;
    const int   bb = (d.x >= 0 && d.x <= 3) ? 0 : 1;
    float* base = out + bb * OUT_HALF + (((d.y * CDIM + d.z) * RDIM + d.w) * NALT);
    const float4 f0 = reinterpret_cast<const float4*>(facc)[i * 2 + 0];
    const float4 f1 = reinterpret_cast<const float4*>(facc)[i * 2 + 1];
    const int4   m0 = reinterpret_cast<const int4*>(mask)[i * 2 + 0];
    const int4   m1 = reinterpret_cast<const int4*>(mask)[i * 2 + 1];
    if (m0.x) atomicAdd(base + 0, vs * fmaxf(f0.x, 0.0f));
    if (m0.y) atomicAdd(base + 1, vs * fmaxf(f0.y, 0.0f));
    if (m0.z) atomicAdd(base + 2, vs * fmaxf(f0.z, 0.0f));
    if (m0.w) atomicAdd(base + 3, vs * fmaxf(f0.w, 0.0f));
    if (m1.x) atomicAdd(base + 4, vs * fmaxf(f1.x, 0.0f));
    if (m1.y) atomicAdd(base + 5, vs * fmaxf(f1.y, 0.0f));
    if (m1.z) atomicAdd(base + 6, vs * fmaxf(f1.z, 0.0f));
    if (m1.w) atomicAdd(base + 7, vs * fmaxf(f1.w, 0.0f));
}

extern "C" void kernel_launch(void* const* d_in, const int* in_sizes, int n_in,
                              void* d_out, int out_size, void* d_ws, size_t ws_size,
                              hipStream_t stream)
{
    // Inputs per setup_inputs():
    // 0: coords (unused)  1: atom_description (N,4) int32
    // 2: alternativeMask (N,8) int32  3: facc (N,8) f32
    // 4: atom_Properties (500,8) f32  5: weight (1,) f32
    const int*   desc   = (const int*)d_in[1];
    const int*   mask   = (const int*)d_in[2];
    const float* facc   = (const float*)d_in[3];
    const float* props  = (const float*)d_in[4];
    const float* weight = (const float*)d_in[5];
    float*       out    = (float*)d_out;

    const int n       = in_sizes[1] / 4;
    const int nblocks = (n + BLK_ATOMS - 1) / BLK_ATOMS;

    // runtime ws layout, 256B-aligned
    auto align256 = [](size_t x) { return (x + 255) & ~(size_t)255; };
    const size_t off_hdr  = 0;
    const size_t off_lidx = align256(off_hdr  + (size_t)nblocks * 64 * 2);
    const size_t off_val  = align256(off_lidx + (size_t)nblocks * BLK_ATOMS * 2);
    const size_t off_part = align256(off_val  + (size_t)nblocks * BLK_ATOMS * 16);

    int nsplit = 0;
    for (int cand = 16; cand >= 1; cand >>= 1) {
        const size_t need = off_part +
            (size_t)NBUCKET * cand * LSLOTS * sizeof(float);
        if (need <= ws_size) { nsplit = cand; break; }
    }

    if (nsplit >= 1) {
        char* ws = (char*)d_ws;
        unsigned short* hdrArr  = (unsigned short*)(ws + off_hdr);
        unsigned short* lidxArr = (unsigned short*)(ws + off_lidx);
        uint4*          valArr  = (uint4*)(ws + off_val);
        float*          part    = (float*)(ws + off_part);

        vdw_compact_kernel<<<nblocks, 256, 0, stream>>>(
            (const int4*)desc, (const int4*)mask, (const float4*)facc,
            props, weight, hdrArr, lidxArr, valArr, n);

        vdw_accum_kernel<<<NBUCKET * nsplit, 256, 0, stream>>>(
            hdrArr, lidxArr, valArr, part, nblocks, nsplit);

        vdw_merge_kernel<<<(OUT_TOTAL + 255) / 256, 256, 0, stream>>>(
            part, out, nsplit);
    } else {
        hipMemsetAsync(d_out, 0, (size_t)out_size * sizeof(float), stream);
        vdw_atomic_kernel<<<(n + 255) / 256, 256, 0, stream>>>(
            desc, mask, facc, props, weight, out, n);
    }
}